// Round 5
// baseline (85.436 us; speedup 1.0000x reference)
//
#include <hip/hip_runtime.h>

#define BATCH   8
#define SHAPE_N 8192
#define SKEL_M  2048

// ws layout (floats):
//   dir1 partials: [b][g][c][2048], b<8, g<4 (A-groups of 2048), c<8  -> 512K
//   dir2 partials: [b][c][2048],    b<8, c<32                         -> 512K
#define WS2_OFF (BATCH * 4 * 8 * 2048)

// ---------------------------------------------------------------------------
// Per-direction worker. min_b d2 = ra + min_b(|b|^2 - 2 a.b): |a|^2 is
// constant w.r.t. the min, so the inner pair is 3 fma + 1 fmin = 4 VALU.
// B-chunk staged in LDS as (-2bx,-2by,-2bz,|b|^2) float4 (ds_read_b128
// broadcast, conflict-free). k=8 A-points/thread: 32 VALU per LDS read
// keeps the CU's single LDS pipe under-subscribed (~75%).
// Each block writes 2048 partial mins to its own ws slice — no atomics,
// no ws pre-init needed.
// ---------------------------------------------------------------------------
template <int SA, int SB, int NA, int NB, int NG, int NC>
__device__ __forceinline__ void cd_dir(
    const float* __restrict__ A, const float* __restrict__ B,
    float* __restrict__ ws, int b, int g, int c, int tid, float4* sB)
{
    // stage B chunk
    {
        const float* q = B + ((size_t)b * NB + c * 256 + tid) * SB;
        const float qx = q[0], qy = q[1], qz = q[2];
        sB[tid] = make_float4(-2.f * qx, -2.f * qy, -2.f * qz,
                              qx * qx + qy * qy + qz * qz);
    }

    const float* Ab = A + ((size_t)b * NA + g * 2048) * SA;
    float ax[8], ay[8], az[8], ra[8], dmin[8];
#pragma unroll
    for (int k = 0; k < 8; ++k) {
        const float* p = Ab + (size_t)(k * 256 + tid) * SA;
        ax[k] = p[0]; ay[k] = p[1]; az[k] = p[2];
        ra[k] = ax[k] * ax[k] + ay[k] * ay[k] + az[k] * az[k];
        dmin[k] = 3.4e38f;
    }
    __syncthreads();

#pragma unroll 4
    for (int i = 0; i < 256; ++i) {
        float4 q = sB[i];
#pragma unroll
        for (int k = 0; k < 8; ++k) {
            float t = fmaf(ax[k], q.x, q.w);   // |b|^2 - 2ax*bx
            t = fmaf(ay[k], q.y, t);
            t = fmaf(az[k], q.z, t);
            dmin[k] = fminf(dmin[k], t);
        }
    }

    float* w = ws + ((size_t)(b * NG + g) * NC + c) * 2048;
#pragma unroll
    for (int k = 0; k < 8; ++k)
        w[k * 256 + tid] = dmin[k] + ra[k];
}

// ---------------------------------------------------------------------------
// Fused: blocks [0,256) dir1 (shape->skel): b=bid>>5, g=(bid>>3)&3, c=bid&7.
//        blocks [256,512) dir2 (skel->shape): b=j>>5, g=0, c=j&31.
// 512 blocks = 2 blocks/CU.
// ---------------------------------------------------------------------------
__global__ __launch_bounds__(256) void cd_main(
    const float* __restrict__ shape, const float* __restrict__ skel,
    float* __restrict__ ws)
{
    __shared__ float4 sB[256];
    const int tid = threadIdx.x;
    const int bid = blockIdx.x;
    if (bid < 256) {
        cd_dir<6, 3, SHAPE_N, SKEL_M, 4, 8>(
            shape, skel, ws, bid >> 5, (bid >> 3) & 3, bid & 7, tid, sB);
    } else {
        const int j = bid - 256;
        cd_dir<3, 6, SKEL_M, SHAPE_N, 1, 32>(
            skel, shape, ws + WS2_OFF, j >> 5, 0, j & 31, tid, sB);
    }
}

// ---------------------------------------------------------------------------
// Finalize: blocks [0,256) each min-reduce 8 chunk-partials for 256 dir1
// points; blocks [256,320) min-reduce 32 partials for 256 dir2 points.
// sqrt(max(.,0)), block reduce, one atomicAdd per block (out pre-zeroed
// by a 4-byte memset node).
// ---------------------------------------------------------------------------
__global__ __launch_bounds__(256) void cd_finalize(
    const float* __restrict__ ws, float* __restrict__ out)
{
    __shared__ float s_wsum[4];
    const int tid = threadIdx.x;
    const int bid = blockIdx.x;
    float m;
    if (bid < 256) {                      // dir1: p = b*8192 + g*2048 + idx
        const int p = bid * 256 + tid;
        const int bg = p >> 11;           // b*4+g
        const int idx = p & 2047;
        const float* w = ws + ((size_t)bg * 8) * 2048 + idx;
        m = w[0];
#pragma unroll
        for (int c = 1; c < 8; ++c) m = fminf(m, w[c * 2048]);
    } else {                              // dir2: p = b*2048 + idx
        const int p = (bid - 256) * 256 + tid;
        const int b = p >> 11;
        const int idx = p & 2047;
        const float* w = ws + WS2_OFF + ((size_t)b * 32) * 2048 + idx;
        m = w[0];
#pragma unroll
        for (int c = 1; c < 32; ++c) m = fminf(m, w[c * 2048]);
    }
    float s = sqrtf(fmaxf(m, 0.f));
    for (int off = 32; off; off >>= 1) s += __shfl_down(s, off, 64);
    const int lane = tid & 63, wave = tid >> 6;
    if (lane == 0) s_wsum[wave] = s;
    __syncthreads();
    if (tid == 0)
        atomicAdd(out, (s_wsum[0] + s_wsum[1] + s_wsum[2] + s_wsum[3]) * 1e-4f);
}

extern "C" void kernel_launch(void* const* d_in, const int* in_sizes, int n_in,
                              void* d_out, int out_size, void* d_ws, size_t ws_size,
                              hipStream_t stream) {
    const float* shape = (const float*)d_in[0];   // (8, 8192, 6) — use first 3
    const float* skel  = (const float*)d_in[1];   // (8, 2048, 3)
    float* out         = (float*)d_out;           // scalar
    float* ws          = (float*)d_ws;            // 1M floats = 4 MB

    hipMemsetAsync(out, 0, sizeof(float), stream);
    cd_main<<<512, 256, 0, stream>>>(shape, skel, ws);
    cd_finalize<<<320, 256, 0, stream>>>(ws, out);
}